// Round 4
// baseline (109.993 us; speedup 1.0000x reference)
//
#include <hip/hip_runtime.h>

#define BS 8
#define NQ 900
#define NC 91
#define TT 200
#define NT (BS*TT)          // 1600 total targets (global columns)
#define NROWS (BS*NQ)       // 7200 rows
#define RPB 4               // rows (queries) per block
#define C_ELEMS ((size_t)NROWS*(size_t)NT)   // 11,520,000

// ---------------- Kernel 1: cost matrix ----------------
// One block = RPB consecutive rows (b,q). LDS holds the 91 focal class-cost
// diffs per row (gathered by tgt id) + pred box in cxcywh and xyxy form.
// Columns processed 4-at-a-time -> float4 stores (16B/lane, coalesced).
__global__ __launch_bounds__(256) void cost_kernel(
    const float* __restrict__ logits,   // (7200, 91)
    const float4* __restrict__ pboxes,  // (7200) cxcywh
    const float4* __restrict__ tboxes,  // (1600) cxcywh
    const int*   __restrict__ tids,     // (1600)
    float* __restrict__ C)              // (7200, 1600)
{
    __shared__ float cls[RPB][NC];
    __shared__ float pb[RPB][8];  // cx,cy,w,h, x1,y1,x2,y2
    const int row0 = blockIdx.x * RPB;
    const int tid  = threadIdx.x;

    // focal-loss class cost diff: pos - neg, per (row, class)
    for (int i = tid; i < RPB * NC; i += 256) {
        const int r = i / NC, c = i - r * NC;
        const float x = logits[(size_t)(row0 + r) * NC + c];
        const float p = 1.0f / (1.0f + expf(-x));
        const float pos = 0.25f * (1.0f - p) * (1.0f - p) * (-logf(p + 1e-8f));
        const float neg = 0.75f * p * p * (-logf(1.0f - p + 1e-8f));
        cls[r][c] = pos - neg;
    }
    if (tid < RPB) {
        const float4 b = pboxes[row0 + tid];
        pb[tid][0] = b.x; pb[tid][1] = b.y; pb[tid][2] = b.z; pb[tid][3] = b.w;
        pb[tid][4] = b.x - 0.5f * b.z; pb[tid][5] = b.y - 0.5f * b.w;
        pb[tid][6] = b.x + 0.5f * b.z; pb[tid][7] = b.y + 0.5f * b.w;
    }
    __syncthreads();

    // 400 column-groups of 4; iter 0 = cols 0..255, iter 1 = cols 256..399
    for (int c4 = tid; c4 < NT / 4; c4 += 256) {
        float4 tb[4]; int id[4];
        float tx1[4], ty1[4], tx2[4], ty2[4], ta[4];
        #pragma unroll
        for (int k = 0; k < 4; ++k) {
            tb[k] = tboxes[c4 * 4 + k];
            id[k] = tids[c4 * 4 + k];
            tx1[k] = tb[k].x - 0.5f * tb[k].z; ty1[k] = tb[k].y - 0.5f * tb[k].w;
            tx2[k] = tb[k].x + 0.5f * tb[k].z; ty2[k] = tb[k].y + 0.5f * tb[k].w;
            ta[k] = (tx2[k] - tx1[k]) * (ty2[k] - ty1[k]);
        }
        #pragma unroll
        for (int r = 0; r < RPB; ++r) {
            const float cx = pb[r][0], cy = pb[r][1], w = pb[r][2], h = pb[r][3];
            const float px1 = pb[r][4], py1 = pb[r][5], px2 = pb[r][6], py2 = pb[r][7];
            const float pa = (px2 - px1) * (py2 - py1);
            float res[4];
            #pragma unroll
            for (int k = 0; k < 4; ++k) {
                const float l1 = fabsf(cx - tb[k].x) + fabsf(cy - tb[k].y)
                               + fabsf(w  - tb[k].z) + fabsf(h  - tb[k].w);
                const float ltx = fmaxf(px1, tx1[k]), lty = fmaxf(py1, ty1[k]);
                const float rbx = fminf(px2, tx2[k]), rby = fminf(py2, ty2[k]);
                const float iw = fmaxf(rbx - ltx, 0.0f), ih = fmaxf(rby - lty, 0.0f);
                const float inter = iw * ih;
                const float uni = pa + ta[k] - inter;
                const float iou = inter / uni;
                const float cltx = fminf(px1, tx1[k]), clty = fminf(py1, ty1[k]);
                const float crbx = fmaxf(px2, tx2[k]), crby = fmaxf(py2, ty2[k]);
                const float cw = fmaxf(crbx - cltx, 0.0f), ch = fmaxf(crby - clty, 0.0f);
                const float ac = cw * ch;
                const float giou = iou - (ac - uni) / ac;
                res[k] = l1 + cls[r][id[k]] - giou;
            }
            float4 out; out.x = res[0]; out.y = res[1]; out.z = res[2]; out.w = res[3];
            reinterpret_cast<float4*>(C)[(size_t)(row0 + r) * (NT / 4) + c4] = out;
        }
    }
}

// order-preserving float->uint key: equal floats -> equal keys, ascending order
__device__ __forceinline__ unsigned long long packkey(float v, int q) {
    unsigned u = __float_as_uint(v);
    u = (u & 0x80000000u) ? ~u : (u | 0x80000000u);
    return ((unsigned long long)u << 32) | (unsigned)q;
}

// ---------------- Kernel 2: argmin over q for each (b,t) ----------------
// One wave per (b,t). Lane l scans q = l, l+64, ...; shuffle min-reduce.
// No workspace needed. Tie-break = smallest q (q packed in low bits).
__global__ __launch_bounds__(64) void argmin_kernel(
    const float* __restrict__ C, float* __restrict__ out, int tail_elems)
{
    const int i = blockIdx.x;          // 0 .. BS*TT-1
    const int b = i / TT;
    const int lane = threadIdx.x;      // 0..63
    const float* base = C + (size_t)b * NQ * NT + (size_t)b * TT + (i - b * TT);
    unsigned long long best = ~0ull;
    for (int q = lane; q < NQ; q += 64) {
        const unsigned long long pk = packkey(base[(size_t)q * NT], q);
        best = best < pk ? best : pk;
    }
    #pragma unroll
    for (int off = 32; off > 0; off >>= 1) {
        const unsigned long long o = __shfl_down(best, off, 64);
        best = best < o ? best : o;
    }
    if (lane == 0) {
        const unsigned q = (unsigned)(best & 0xffffffffu);
        float* tail = out + C_ELEMS;
        if (tail_elems >= 3200) {
            reinterpret_cast<long long*>(tail)[i] = (long long)q;   // raw int64
        } else if (tail_elems >= 1600) {
            tail[i] = (float)q;                                     // f32-cast idx
        }
    }
}

extern "C" void kernel_launch(void* const* d_in, const int* in_sizes, int n_in,
                              void* d_out, int out_size, void* d_ws, size_t ws_size,
                              hipStream_t stream) {
    const float*  logits = (const float*)d_in[0];   // (8,900,91)
    const float4* pboxes = (const float4*)d_in[1];  // (8,900,4)
    const float4* tboxes = (const float4*)d_in[2];  // (8,200,4)
    const int*    tids   = (const int*)d_in[3];     // (8,200)
    float* C = (float*)d_out;
    (void)d_ws; (void)ws_size;

    cost_kernel<<<NROWS / RPB, 256, 0, stream>>>(logits, pboxes, tboxes, tids, C);
    const int tail = out_size - (int)C_ELEMS;
    argmin_kernel<<<BS * TT, 64, 0, stream>>>(C, C, tail);
}

// Round 5
// 104.210 us; speedup vs baseline: 1.0555x; 1.0555x over previous
//
#include <hip/hip_runtime.h>

#define BS 8
#define NQ 900
#define NC 91
#define TT 200
#define NT (BS*TT)          // 1600 global columns == 1600 (b,t) slots
#define NROWS (BS*NQ)       // 7200
#define RPB 8               // rows per block
#define NBLK (NROWS/RPB)    // 900 blocks
#define C_ELEMS ((size_t)NROWS*(size_t)NT)   // 11,520,000

// v_rcp_f32 + 1 Newton iteration: rel err ~1e-7, vs full div ~12 extra instrs
__device__ __forceinline__ float fastrcp(float x) {
    float r = __builtin_amdgcn_rcpf(x);
    return r * fmaf(-x, r, 2.0f);
}

// order-preserving float->uint key; q in low bits => min == first-occurrence argmin
__device__ __forceinline__ unsigned long long packkey(float v, int q) {
    unsigned u = __float_as_uint(v);
    u = (u & 0x80000000u) ? ~u : (u | 0x80000000u);
    return ((unsigned long long)u << 32) | (unsigned)q;
}

__global__ void init_slots(unsigned long long* __restrict__ slots) {
    const int i = blockIdx.x * blockDim.x + threadIdx.x;
    if (i < NT) slots[i] = ~0ull;
}

// ---------------- fused cost + diagonal argmin ----------------
// Block = 8 consecutive global rows. LDS: 91 focal class-cost diffs per row +
// pred boxes (cxcywh & xyxy). Columns 4-at-a-time -> float4 stores.
// Diagonal columns (col/200 == row's batch) feed a packed-u64 atomicMin.
__global__ __launch_bounds__(256) void cost_argmin_kernel(
    const float* __restrict__ logits,   // (7200, 91)
    const float4* __restrict__ pboxes,  // (7200) cxcywh
    const float4* __restrict__ tboxes,  // (1600) cxcywh
    const int*   __restrict__ tids,     // (1600)
    float* __restrict__ C,              // (7200, 1600)
    unsigned long long* __restrict__ slots) // (1600)
{
    __shared__ float cls[RPB][NC];
    __shared__ float pb[RPB][8];  // cx,cy,w,h, x1,y1,x2,y2
    const int row0 = blockIdx.x * RPB;
    const int tid  = threadIdx.x;

    for (int i = tid; i < RPB * NC; i += 256) {
        const int r = i / NC, c = i - r * NC;
        const float x = logits[(size_t)(row0 + r) * NC + c];
        const float p = 1.0f / (1.0f + expf(-x));
        const float pos = 0.25f * (1.0f - p) * (1.0f - p) * (-logf(p + 1e-8f));
        const float neg = 0.75f * p * p * (-logf(1.0f - p + 1e-8f));
        cls[r][c] = pos - neg;
    }
    if (tid < RPB) {
        const float4 b = pboxes[row0 + tid];
        pb[tid][0] = b.x; pb[tid][1] = b.y; pb[tid][2] = b.z; pb[tid][3] = b.w;
        pb[tid][4] = b.x - 0.5f * b.z; pb[tid][5] = b.y - 0.5f * b.w;
        pb[tid][6] = b.x + 0.5f * b.z; pb[tid][7] = b.y + 0.5f * b.w;
    }
    __syncthreads();

    // 400 column-groups of 4 over 256 threads (iter 2 ragged)
    for (int c4 = tid; c4 < NT / 4; c4 += 256) {
        float4 tb[4];
        float tx1[4], ty1[4], tx2[4], ty2[4], ta[4];
        float clsv[4];
        #pragma unroll
        for (int k = 0; k < 4; ++k) {
            tb[k] = tboxes[c4 * 4 + k];
            tx1[k] = tb[k].x - 0.5f * tb[k].z; ty1[k] = tb[k].y - 0.5f * tb[k].w;
            tx2[k] = tb[k].x + 0.5f * tb[k].z; ty2[k] = tb[k].y + 0.5f * tb[k].w;
            ta[k] = (tx2[k] - tx1[k]) * (ty2[k] - ty1[k]);
        }
        int id[4];
        #pragma unroll
        for (int k = 0; k < 4; ++k) id[k] = tids[c4 * 4 + k];

        const int cdiv = c4 / 50;  // batch owning these 4 cols' diagonal (200%4==0: no straddle)
        unsigned long long mk[4] = {~0ull, ~0ull, ~0ull, ~0ull};
        bool any = false;

        #pragma unroll
        for (int r = 0; r < RPB; ++r) {
            const int grow = row0 + r;
            const float cx = pb[r][0], cy = pb[r][1], w = pb[r][2], h = pb[r][3];
            const float px1 = pb[r][4], py1 = pb[r][5], px2 = pb[r][6], py2 = pb[r][7];
            const float pa = (px2 - px1) * (py2 - py1);
            #pragma unroll
            for (int k = 0; k < 4; ++k) clsv[k] = cls[r][id[k]];
            float res[4];
            #pragma unroll
            for (int k = 0; k < 4; ++k) {
                const float l1 = fabsf(cx - tb[k].x) + fabsf(cy - tb[k].y)
                               + fabsf(w  - tb[k].z) + fabsf(h  - tb[k].w);
                const float ltx = fmaxf(px1, tx1[k]), lty = fmaxf(py1, ty1[k]);
                const float rbx = fminf(px2, tx2[k]), rby = fminf(py2, ty2[k]);
                const float iw = fmaxf(rbx - ltx, 0.0f), ih = fmaxf(rby - lty, 0.0f);
                const float inter = iw * ih;
                const float uni = pa + ta[k] - inter;
                const float cltx = fminf(px1, tx1[k]), clty = fminf(py1, ty1[k]);
                const float crbx = fmaxf(px2, tx2[k]), crby = fmaxf(py2, ty2[k]);
                const float cw = fmaxf(crbx - cltx, 0.0f), ch = fmaxf(crby - clty, 0.0f);
                const float ac = cw * ch;
                const float giou = inter * fastrcp(uni) - (ac - uni) * fastrcp(ac);
                res[k] = l1 + clsv[k] - giou;
            }
            float4 out; out.x = res[0]; out.y = res[1]; out.z = res[2]; out.w = res[3];
            reinterpret_cast<float4*>(C)[(size_t)grow * (NT / 4) + c4] = out;

            const int brow = grow / NQ;          // row's batch (block may straddle)
            if (brow == cdiv) {
                const int q = grow - brow * NQ;
                any = true;
                #pragma unroll
                for (int k = 0; k < 4; ++k) {
                    const unsigned long long pk = packkey(res[k], q);
                    mk[k] = mk[k] < pk ? mk[k] : pk;
                }
            }
        }
        if (any) {
            #pragma unroll
            for (int k = 0; k < 4; ++k)
                atomicMin(&slots[c4 * 4 + k], mk[k]);
        }
    }
}

// ---------------- finalize: slots -> idx tail ----------------
__global__ void write_idx(const unsigned long long* __restrict__ slots,
                          float* __restrict__ out, int tail_elems) {
    const int i = blockIdx.x * blockDim.x + threadIdx.x;
    if (i >= NT) return;
    const unsigned q = (unsigned)(slots[i] & 0xffffffffu);
    float* tail = out + C_ELEMS;
    if (tail_elems >= 3200) {
        reinterpret_cast<long long*>(tail)[i] = (long long)q;   // raw int64
    } else if (tail_elems >= 1600) {
        tail[i] = (float)q;                                     // f32-cast idx
    }
}

extern "C" void kernel_launch(void* const* d_in, const int* in_sizes, int n_in,
                              void* d_out, int out_size, void* d_ws, size_t ws_size,
                              hipStream_t stream) {
    const float*  logits = (const float*)d_in[0];   // (8,900,91)
    const float4* pboxes = (const float4*)d_in[1];  // (8,900,4)
    const float4* tboxes = (const float4*)d_in[2];  // (8,200,4)
    const int*    tids   = (const int*)d_in[3];     // (8,200)
    float* C = (float*)d_out;
    unsigned long long* slots = (unsigned long long*)d_ws; // 12.8 KB of d_ws

    init_slots<<<(NT + 255) / 256, 256, 0, stream>>>(slots);
    cost_argmin_kernel<<<NBLK, 256, 0, stream>>>(logits, pboxes, tboxes, tids, C, slots);
    const int tail = out_size - (int)C_ELEMS;
    write_idx<<<(NT + 255) / 256, 256, 0, stream>>>(slots, C, tail);
}

// Round 6
// 102.187 us; speedup vs baseline: 1.0764x; 1.0198x over previous
//
#include <hip/hip_runtime.h>

#define BS 8
#define NQ 900
#define NC 91
#define TT 200
#define NT (BS*TT)          // 1600 global columns == 1600 (b,t) slots
#define NROWS (BS*NQ)       // 7200
#define RPB 8               // rows per row-group
#define NRG (NROWS/RPB)     // 900 row-groups
#define HCG 200             // c4-groups per block (half of 400)
#define C_ELEMS ((size_t)NROWS*(size_t)NT)   // 11,520,000

// v_rcp_f32 + 1 Newton iteration: rel err ~1e-7
__device__ __forceinline__ float fastrcp(float x) {
    float r = __builtin_amdgcn_rcpf(x);
    return r * fmaf(-x, r, 2.0f);
}

// order-preserving float->uint key; q in low bits => min == first-occurrence argmin
__device__ __forceinline__ unsigned long long packkey(float v, int q) {
    unsigned u = __float_as_uint(v);
    u = (u & 0x80000000u) ? ~u : (u | 0x80000000u);
    return ((unsigned long long)u << 32) | (unsigned)q;
}

__global__ void init_slots(unsigned long long* __restrict__ slots) {
    const int i = blockIdx.x * blockDim.x + threadIdx.x;
    if (i < NT) slots[i] = ~0ull;
}

// ---------------- fused cost + diagonal argmin ----------------
// Grid = 900 row-groups x 2 column-halves. Block: 256 threads; threads 0..199
// each own ONE 4-column group (no ragged re-iteration) and loop 8 rows with
// target boxes held in registers. Diagonal columns feed packed-u64 atomicMin.
__global__ __launch_bounds__(256) void cost_argmin_kernel(
    const float* __restrict__ logits,   // (7200, 91)
    const float4* __restrict__ pboxes,  // (7200) cxcywh
    const float4* __restrict__ tboxes,  // (1600) cxcywh
    const int*   __restrict__ tids,     // (1600)
    float* __restrict__ C,              // (7200, 1600)
    unsigned long long* __restrict__ slots) // (1600)
{
    __shared__ float cls[RPB][NC];
    __shared__ float pb[RPB][8];  // cx,cy,w,h, x1,y1,x2,y2
    const int rg   = blockIdx.x >> 1;
    const int half = blockIdx.x & 1;
    const int row0 = rg * RPB;
    const int tid  = threadIdx.x;

    for (int i = tid; i < RPB * NC; i += 256) {
        const int r = i / NC, c = i - r * NC;
        const float x = logits[(size_t)(row0 + r) * NC + c];
        const float p = 1.0f / (1.0f + expf(-x));
        const float pos = 0.25f * (1.0f - p) * (1.0f - p) * (-logf(p + 1e-8f));
        const float neg = 0.75f * p * p * (-logf(1.0f - p + 1e-8f));
        cls[r][c] = pos - neg;
    }
    if (tid < RPB) {
        const float4 b = pboxes[row0 + tid];
        pb[tid][0] = b.x; pb[tid][1] = b.y; pb[tid][2] = b.z; pb[tid][3] = b.w;
        pb[tid][4] = b.x - 0.5f * b.z; pb[tid][5] = b.y - 0.5f * b.w;
        pb[tid][6] = b.x + 0.5f * b.z; pb[tid][7] = b.y + 0.5f * b.w;
    }
    __syncthreads();

    if (tid >= HCG) return;
    const int c4 = half * HCG + tid;    // global 4-column group, 0..399

    float4 tb[4];
    float tx1[4], ty1[4], tx2[4], ty2[4], ta[4];
    int id[4];
    #pragma unroll
    for (int k = 0; k < 4; ++k) {
        tb[k] = tboxes[c4 * 4 + k];
        id[k] = tids[c4 * 4 + k];
        tx1[k] = tb[k].x - 0.5f * tb[k].z; ty1[k] = tb[k].y - 0.5f * tb[k].w;
        tx2[k] = tb[k].x + 0.5f * tb[k].z; ty2[k] = tb[k].y + 0.5f * tb[k].w;
        ta[k] = (tx2[k] - tx1[k]) * (ty2[k] - ty1[k]);
    }

    const int cdiv = c4 / 50;  // batch owning these 4 cols' diagonal (200%4==0)
    unsigned long long mk[4] = {~0ull, ~0ull, ~0ull, ~0ull};
    bool any = false;

    #pragma unroll
    for (int r = 0; r < RPB; ++r) {
        const int grow = row0 + r;
        const float cx = pb[r][0], cy = pb[r][1], w = pb[r][2], h = pb[r][3];
        const float px1 = pb[r][4], py1 = pb[r][5], px2 = pb[r][6], py2 = pb[r][7];
        const float pa = (px2 - px1) * (py2 - py1);
        float res[4];
        #pragma unroll
        for (int k = 0; k < 4; ++k) {
            const float l1 = fabsf(cx - tb[k].x) + fabsf(cy - tb[k].y)
                           + fabsf(w  - tb[k].z) + fabsf(h  - tb[k].w);
            const float ltx = fmaxf(px1, tx1[k]), lty = fmaxf(py1, ty1[k]);
            const float rbx = fminf(px2, tx2[k]), rby = fminf(py2, ty2[k]);
            const float iw = fmaxf(rbx - ltx, 0.0f), ih = fmaxf(rby - lty, 0.0f);
            const float inter = iw * ih;
            const float uni = pa + ta[k] - inter;
            const float cltx = fminf(px1, tx1[k]), clty = fminf(py1, ty1[k]);
            const float crbx = fmaxf(px2, tx2[k]), crby = fmaxf(py2, ty2[k]);
            const float cw = fmaxf(crbx - cltx, 0.0f), ch = fmaxf(crby - clty, 0.0f);
            const float ac = cw * ch;
            const float giou = inter * fastrcp(uni) - (ac - uni) * fastrcp(ac);
            res[k] = l1 + cls[r][id[k]] - giou;
        }
        float4 out; out.x = res[0]; out.y = res[1]; out.z = res[2]; out.w = res[3];
        reinterpret_cast<float4*>(C)[(size_t)grow * (NT / 4) + c4] = out;

        const int brow = grow / NQ;      // row's batch (group may straddle)
        if (brow == cdiv) {
            const int q = grow - brow * NQ;
            any = true;
            #pragma unroll
            for (int k = 0; k < 4; ++k) {
                const unsigned long long pk = packkey(res[k], q);
                mk[k] = mk[k] < pk ? mk[k] : pk;
            }
        }
    }
    if (any) {
        #pragma unroll
        for (int k = 0; k < 4; ++k)
            atomicMin(&slots[c4 * 4 + k], mk[k]);
    }
}

// ---------------- finalize: slots -> idx tail ----------------
__global__ void write_idx(const unsigned long long* __restrict__ slots,
                          float* __restrict__ out, int tail_elems) {
    const int i = blockIdx.x * blockDim.x + threadIdx.x;
    if (i >= NT) return;
    const unsigned q = (unsigned)(slots[i] & 0xffffffffu);
    float* tail = out + C_ELEMS;
    if (tail_elems >= 3200) {
        reinterpret_cast<long long*>(tail)[i] = (long long)q;   // raw int64
    } else if (tail_elems >= 1600) {
        tail[i] = (float)q;                                     // f32-cast idx
    }
}

extern "C" void kernel_launch(void* const* d_in, const int* in_sizes, int n_in,
                              void* d_out, int out_size, void* d_ws, size_t ws_size,
                              hipStream_t stream) {
    const float*  logits = (const float*)d_in[0];   // (8,900,91)
    const float4* pboxes = (const float4*)d_in[1];  // (8,900,4)
    const float4* tboxes = (const float4*)d_in[2];  // (8,200,4)
    const int*    tids   = (const int*)d_in[3];     // (8,200)
    float* C = (float*)d_out;
    unsigned long long* slots = (unsigned long long*)d_ws; // 12.8 KB of d_ws

    init_slots<<<(NT + 255) / 256, 256, 0, stream>>>(slots);
    cost_argmin_kernel<<<NRG * 2, 256, 0, stream>>>(logits, pboxes, tboxes, tids, C, slots);
    const int tail = out_size - (int)C_ELEMS;
    write_idx<<<(NT + 255) / 256, 256, 0, stream>>>(slots, C, tail);
}